// Round 24
// baseline (74.226 us; speedup 1.0000x reference)
//
#include <hip/hip_runtime.h>
#include <hip/hip_bf16.h>

// DenseGraphSimpleOpEdgeFlow — R24: R23 with fused __launch_bounds__(512,4) -> (512,2).
// R23 profile: VGPR_Count=64, WRITE 5MB (output 3MB) -- the allocator squeezes to 64 regs
// chasing 8 waves/SIMD that LDS (80,896B -> 2 blocks/CU = 4 waves/SIMD) can never grant,
// paying ~2MB scratch on the critical path. Same body at cap-256 (R14) allocated 88 regs,
// zero spill. Cap 256 lets it land at its natural ~90-110 (<=128 keeps 4 waves/SIMD).
// Everything else R23-verbatim: 1 barrier/tile; phase g = {store(g-1)+S2 prefetch |
// issue(g+2) | counted vmcnt (wj0=4/wj1=3) | convert(g+1) | setprio(1) MFMA+epilogue(g)
// setprio(0)}; 3-deep F32buf; d48 mask fold (attn=rcp(1+exp2(acc))); bias in C-init;
// wave-contiguous S2; XOR-swizzled Atile; global_load_lds; mcode 2-bit/tile.
// Requires ws_size >= 64*96*128*4 = 3,145,728 bytes (S2 scratch).

#define B_ 64
#define N_ 96
#define F_ 128
#define D_ 48
#define G_ 12
#define NGRP (N_ / G_)   // 8 groups per b -> grid = 64*8 = 512 blocks = 2/CU

typedef __attribute__((ext_vector_type(8))) short short8;
typedef __attribute__((ext_vector_type(4))) float f32x4;

#if __has_builtin(__builtin_amdgcn_exp2f)
#define EXP2(x) __builtin_amdgcn_exp2f(x)
#else
#define EXP2(x) exp2f(x)
#endif

__device__ __forceinline__ void gload_lds16(const void* g, void* l) {
    __builtin_amdgcn_global_load_lds(
        (const __attribute__((address_space(1))) void*)g,
        (__attribute__((address_space(3))) void*)l, 16, 0, 0);
}

// S2 layout (wave-contiguous reads): float2 index (((b*6 + mt)*4 + r)*4 + lg)*64 + fbp
__device__ __forceinline__ size_t s2i(int b, int mt, int r, int lg, int fbp) {
    return ((((size_t)b * 6 + mt) * 4 + r) * 4 + lg) * 64 + fbp;
}

__device__ __forceinline__ unsigned bfbits(float x) {
    union { __hip_bfloat16 h; unsigned short u; } cv;
    cv.h = __float2bfloat16(x);
    return (unsigned)cv.u;
}

// ---------------- Kernel 1: support = inputs @ weight, written in S2 fragment layout ----------------
__global__ __launch_bounds__(256, 4) void support_kernel(
    const float* __restrict__ inputs, const float* __restrict__ weight,
    float2* __restrict__ S2)
{
    __shared__ float in_lds[16 * F_];
    const int tid = threadIdx.x;
    const int row0 = blockIdx.x * 16;
    ((float4*)in_lds)[tid]       = ((const float4*)(inputs + (size_t)row0 * F_))[tid];
    ((float4*)in_lds)[tid + 256] = ((const float4*)(inputs + (size_t)row0 * F_))[tid + 256];
    __syncthreads();
    const int rl = tid >> 4, f0 = (tid & 15) * 8;
    float acc[8] = {0.f,0.f,0.f,0.f,0.f,0.f,0.f,0.f};
    #pragma unroll 4
    for (int k = 0; k < F_; ++k) {
        const float a = in_lds[rl * F_ + k];
        const float4 w0 = *(const float4*)(weight + k * F_ + f0);
        const float4 w1 = *(const float4*)(weight + k * F_ + f0 + 4);
        acc[0] += a * w0.x; acc[1] += a * w0.y; acc[2] += a * w0.z; acc[3] += a * w0.w;
        acc[4] += a * w1.x; acc[5] += a * w1.y; acc[6] += a * w1.z; acc[7] += a * w1.w;
    }
    const int R = row0 + rl;
    const int b = R / N_, j = R - b * N_;
    const int mt = j >> 4, lg = (j >> 2) & 3, r = j & 3;
    #pragma unroll
    for (int q = 0; q < 4; ++q) {
        const int fbp = (f0 >> 1) + q;   // f-pair index
        S2[s2i(b, mt, r, lg, fbp)] = make_float2(acc[2 * q], acc[2 * q + 1]);
    }
}

// ---------------- Kernel 2: fused attn-GEMM, overlapped convert/compute, 1 barrier/tile ----------------
// 8 waves = (4 f-slices) x (2 mt-halves). MFMA 16x16x32 k-slot fill d = ks*32+lg*8+e,
// identical for A and B (physical-k permutation cancels). C/D (HW-verified):
// col = lane&15 (-> f-pair), row = (lane>>4)*4 + reg (-> j).
__global__ __launch_bounds__(512, 2) void fused_kernel(
    const float* __restrict__ op_emb,
    const unsigned* __restrict__ adjw,      // raw 32-bit view of adj (int32 or int64)
    const float* __restrict__ attn_w,
    const float* __restrict__ attn_b,
    const float* __restrict__ self_op,
    const float2* __restrict__ S2,
    float* __restrict__ out)
{
    __shared__ __align__(16) float F32buf[3][N_ * D_];          // 3 x 18,432 B raw fp32 tiles
    __shared__ __align__(16) unsigned short Atile[2][N_ * 64];  // 2 x 12,288 B bf16; d48 mask
    __shared__ __align__(8)  float2 Ppart[2][4][16];            // wj=1 partials, parity

    const int tid  = threadIdx.x;
    const int lane = tid & 63;
    const int wid  = tid >> 6;      // wave 0..7
    const int wf   = wid & 3;       // f-slice
    const int wj   = wid >> 2;      // mt-half: mt in [3*wj, 3*wj+3)
    const int lg   = lane >> 4;
    const int lm   = lane & 15;
    const int fb   = wf * 32 + lm * 2;
    const int fbp  = wf * 16 + lm;

    const int blk = blockIdx.x;
    const int b   = blk / NGRP;
    const int grp = blk - b * NGRP;
    const int i0  = grp * G_;

    const float kNL2E = -1.44269504088896f;

    // --- adj dtype sniff: int64 little-endian has all-zero high words (values 0..4) ---
    const unsigned probe = adjw[2 * lane + 1];
    const bool use32 = __any(probe != 0);

    // issue EXACTLY 3 direct-to-LDS 1KB copies per wave for tile i -> F32buf[pb]
    auto issue_tile = [&](int i, int pb) {
        const char* gbase = (const char*)(op_emb + (size_t)(b * N_ + i) * N_ * D_);
        char* lbase = (char*)(&F32buf[pb][0]);
        #pragma unroll
        for (int c0 = 0; c0 < 3; ++c0) {
            int c = wid + 8 * c0;
            c = (c < 18) ? c : 17;          // clamp keeps per-wave vmcnt uniform
            gload_lds16(gbase + c * 1024 + lane * 16, lbase + c * 1024);
        }
    };

    // ---- prologue: issue tiles 0,1 ----
    issue_tile(i0, 0);
    issue_tile(i0 + 1, 1);

    // ---- mask codes, packed 2-bit per tile in a register (thread tid<96 owns row j=tid) ----
    unsigned mcode = 0;
    if (tid < N_) {
        #pragma unroll
        for (int g2 = 0; g2 < G_; ++g2) {
            const size_t idx = (size_t)(b * N_ + i0 + g2) * N_ + tid;
            int a = use32 ? (int)adjw[idx] : (int)adjw[2 * idx];
            a += (tid == i0 + g2) ? 1 : 0;
            const unsigned code = (a == 0) ? 0u : ((a == 1) ? 1u : 2u);
            mcode |= code << (2 * g2);
        }
    }

    // --- B fragments (attn_w pre-scaled by -log2e; d==48 -> 1.0) + bias ---
    short8 bfrag[2][2];
    float  bbias[2];
    {
        const float2 bb = *(const float2*)(attn_b + fb);
        bbias[0] = bb.x * kNL2E;
        bbias[1] = bb.y * kNL2E;
        #pragma unroll
        for (int ks = 0; ks < 2; ++ks) {
            short8 v0, v1;
            #pragma unroll
            for (int e = 0; e < 8; ++e) {
                const int d = ks * 32 + lg * 8 + e;
                if (d < D_) {
                    const float2 w = *(const float2*)(attn_w + d * F_ + fb);
                    v0[e] = (short)bfbits(w.x * kNL2E);
                    v1[e] = (short)bfbits(w.y * kNL2E);
                } else {
                    const unsigned one = (d == D_) ? bfbits(1.0f) : 0u;  // mask-slot weight
                    v0[e] = (short)one;
                    v1[e] = (short)one;
                }
            }
            bfrag[0][ks] = v0;
            bfrag[1][ks] = v1;
        }
    }

    // --- support fragments for THIS wave's mt-half (fp32, 24 regs) ---
    float2 sfrag[3][4];
    #pragma unroll
    for (int s = 0; s < 3; ++s)
        #pragma unroll
        for (int r = 0; r < 4; ++r)
            sfrag[s][r] = S2[s2i(b, 3 * wj + s, r, lg, fbp)];

    // --- zero Atile k-pad d in [50,64) of both buffers once ---
    for (int v = tid; v < 2 * N_ * 7; v += 512) {
        const int t = v / (N_ * 7);
        const int vv = v - t * (N_ * 7);
        const int j = vv / 7, q = vv - 7 * j;
        const int byte = j * 128 + ((100 + q * 4) ^ ((j & 7) << 4));
        *(unsigned*)((char*)(&Atile[t][0]) + byte) = 0u;
    }

    __syncthreads();   // drains tiles 0,1 + adj loads + pad writes (once per block)

    // convert tile gg: F32buf[gg%3] -> bf16 swizzled Atile[gg&1]; diag <- self_op; d48 <- mask
    auto convert_tile = [&](int gg) {
        const int ic = i0 + gg;
        const float* fsrc = &F32buf[gg % 3][0];
        #pragma unroll
        for (int s = 0; s < 3; ++s) {
            const int w = tid + s * 512;
            if (w < N_ * 12) {
                const int j = w / 12, c = w - 12 * j;
                float4 p;
                if (j == ic) p = *(const float4*)(self_op + c * 4);
                else         p = *(const float4*)((const char*)fsrc + 16 * w);
                const int byte = j * 128 + ((c * 8) ^ ((j & 7) << 4));
                *(uint2*)((char*)(&Atile[gg & 1][0]) + byte) =
                    make_uint2(bfbits(p.x) | (bfbits(p.y) << 16),
                               bfbits(p.z) | (bfbits(p.w) << 16));
            }
        }
        if (tid < N_) {
            const unsigned code = (mcode >> (2 * gg)) & 3u;   // shift>=24 -> 0 (dead buffer)
            // 0 -> +126 (attn 0 via exp2 saturation), 1 -> -126 (attn 1), 2 -> 0 (sigmoid)
            const unsigned bits = (code == 0) ? 0x42FCu : ((code == 1) ? 0xC2FCu : 0u);
            const int byte = tid * 128 + (96 ^ ((tid & 7) << 4));
            *(unsigned*)((char*)(&Atile[gg & 1][0]) + byte) = bits;
        }
    };

    // ---- prologue part 2: convert tile 0, make visible ----
    convert_tile(0);
    asm volatile("s_waitcnt lgkmcnt(0)" ::: "memory");
    __builtin_amdgcn_s_barrier();

    float osum_prev0 = 0.f, osum_prev1 = 0.f;

    #pragma unroll 1
    for (int g = 0; g < G_; ++g) {
        const int i = i0 + g;

        // ---- A: residual load + deferred store of tile g-1 (BEFORE issue: its implied
        //         vmcnt only drains tile-g+1 loads, which convert needs right after) ----
        if (wj == 0 && lg == 0) {
            const int ip = (g > 0) ? (i - 1) : i0;
            const float2 srv = S2[s2i(b, ip >> 4, ip & 3, (ip >> 2) & 3, fbp)];
            if (g > 0) {
                const float2 pp = Ppart[(g - 1) & 1][wf][lm];
                float2 o;
                o.x = osum_prev0 + pp.x + srv.x;
                o.y = osum_prev1 + pp.y + srv.y;
                *(float2*)(out + (size_t)(b * N_ + ip) * F_ + fb) = o;
            }
        }

        // ---- B: issue tile g+2 (clamped at tail; uniform 3 loads/wave) ----
        {
            const int inx = (g + 2 < G_) ? (g + 2) : (G_ - 1);
            issue_tile(i0 + inx, (g + 2) % 3);
        }

        // ---- W: counted wait -> tile g+1's loads landed; g+2's stay in flight ----
        if (wj == 0) asm volatile("s_waitcnt vmcnt(4)" ::: "memory");
        else         asm volatile("s_waitcnt vmcnt(3)" ::: "memory");

        // ---- C: convert tile g+1 into Atile[(g+1)&1] (overlaps compute below) ----
        convert_tile(g + 1);

        // ---- D: compute tile g from Atile[g&1]: 3 mt-slabs, MFMA + sigmoid ----
        __builtin_amdgcn_s_setprio(1);
        float osum0 = 0.f, osum1 = 0.f;
        #pragma unroll
        for (int s = 0; s < 3; ++s) {
            const int mt  = 3 * wj + s;
            const int jr  = mt * 16 + lm;
            const int swz = (lm & 7) << 4;
            const char* base = (const char*)(&Atile[g & 1][0]) + jr * 128;
            const short8 a0 = *(const short8*)(base + (( 0 + lg * 16) ^ swz));
            const short8 a1 = *(const short8*)(base + ((64 + lg * 16) ^ swz));
            f32x4 c0 = (f32x4){bbias[0], bbias[0], bbias[0], bbias[0]};
            f32x4 c1 = (f32x4){bbias[1], bbias[1], bbias[1], bbias[1]};
            c0 = __builtin_amdgcn_mfma_f32_16x16x32_bf16(a0, bfrag[0][0], c0, 0, 0, 0);
            c0 = __builtin_amdgcn_mfma_f32_16x16x32_bf16(a1, bfrag[0][1], c0, 0, 0, 0);
            c1 = __builtin_amdgcn_mfma_f32_16x16x32_bf16(a0, bfrag[1][0], c1, 0, 0, 0);
            c1 = __builtin_amdgcn_mfma_f32_16x16x32_bf16(a1, bfrag[1][1], c1, 0, 0, 0);
            #pragma unroll
            for (int r = 0; r < 4; ++r) {
                const float s0 = __builtin_amdgcn_rcpf(1.f + EXP2(c0[r]));
                const float s1 = __builtin_amdgcn_rcpf(1.f + EXP2(c1[r]));
                osum0 = __builtin_fmaf(s0, sfrag[s][r].x, osum0);
                osum1 = __builtin_fmaf(s1, sfrag[s][r].y, osum1);
            }
        }
        __builtin_amdgcn_s_setprio(0);
        // reduce over the 4 lg j-subsets within the wave
        osum0 += __shfl_xor(osum0, 16);
        osum0 += __shfl_xor(osum0, 32);
        osum1 += __shfl_xor(osum1, 16);
        osum1 += __shfl_xor(osum1, 32);
        // wj=1 publishes its half (consumed next iteration, after the barrier)
        if (wj == 1 && lg == 0)
            Ppart[g & 1][wf][lm] = make_float2(osum0, osum1);
        osum_prev0 = osum0;
        osum_prev1 = osum1;

        // ---- single barrier: convert(g+1) + Ppart visible; Atile[g&1] free for reuse ----
        asm volatile("s_waitcnt lgkmcnt(0)" ::: "memory");
        __builtin_amdgcn_s_barrier();
    }

    // ---- epilogue: store the last tile ----
    if (wj == 0 && lg == 0) {
        const int ip = i0 + G_ - 1;
        const float2 pp = Ppart[(G_ - 1) & 1][wf][lm];
        const float2 sr = S2[s2i(b, ip >> 4, ip & 3, (ip >> 2) & 3, fbp)];
        float2 o;
        o.x = osum_prev0 + pp.x + sr.x;
        o.y = osum_prev1 + pp.y + sr.y;
        *(float2*)(out + (size_t)(b * N_ + ip) * F_ + fb) = o;
    }
}

extern "C" void kernel_launch(void* const* d_in, const int* in_sizes, int n_in,
                              void* d_out, int out_size, void* d_ws, size_t ws_size,
                              hipStream_t stream) {
    const float*    inputs  = (const float*)d_in[0];
    const unsigned* adjw    = (const unsigned*)d_in[1];
    const float*    op_emb  = (const float*)d_in[2];
    const float*    weight  = (const float*)d_in[3];
    const float*    attn_w  = (const float*)d_in[4];
    const float*    attn_b  = (const float*)d_in[5];
    const float*    self_op = (const float*)d_in[6];
    float* out = (float*)d_out;
    float2* S2 = (float2*)d_ws;  // fragment-layout support, 3,145,728 bytes

    support_kernel<<<(B_ * N_) / 16, 256, 0, stream>>>(inputs, weight, S2);
    fused_kernel<<<B_ * NGRP, 512, 0, stream>>>(op_emb, adjw, attn_w, attn_b, self_op,
                                                S2, out);
}

// Round 25
// 59.200 us; speedup vs baseline: 1.2538x; 1.2538x over previous
//
#include <hip/hip_runtime.h>
#include <hip/hip_bf16.h>

// DenseGraphSimpleOpEdgeFlow — R25: R23 base + 4-way shared-rcp sigmoid (trans-pipe diet).
// R24's (512,2) regressed (74us) -> launch bounds reverted to (512,4); spill theory dead.
// New arithmetic: 75.5M sigmoids x 2 trans ops = ~31us of quarter-rate trans-pipe per CU --
// invisible in VALUBusy, fits warm==cold + structure-invariant wall + R12's 40us probe floor.
// Fix: per r-quad compute d_r = 1+exp2(acc_r), ONE rcp(d0 d1 d2 d3), recover each sigmoid
// as R * (product of other three) via prefix/suffix products: 8 exp2 + 2 rcp per slab
// (was 8+8), +18 muls on the slack VALU pipe. Mask offsets +-126 -> +-20 so the 4-products
// can't overflow (worst ~3.5e34 << FLT_MAX; all-masked inf -> R=0 -> sig=0 = correct;
// masked sig <= 4e-4, skip err 1e-6, threshold 0.605).
// Keeps: 1 barrier/tile, convert(g+1)||compute(g), 3-deep F32buf, counted vmcnt (wj0=4/
// wj1=3), d48 mask fold, bias in C-init, wave-contiguous S2, XOR Atile, setprio, mcode.
// Requires ws_size >= 64*96*128*4 = 3,145,728 bytes (S2 scratch).

#define B_ 64
#define N_ 96
#define F_ 128
#define D_ 48
#define G_ 12
#define NGRP (N_ / G_)   // 8 groups per b -> grid = 64*8 = 512 blocks = 2/CU

typedef __attribute__((ext_vector_type(8))) short short8;
typedef __attribute__((ext_vector_type(4))) float f32x4;

#if __has_builtin(__builtin_amdgcn_exp2f)
#define EXP2(x) __builtin_amdgcn_exp2f(x)
#else
#define EXP2(x) exp2f(x)
#endif

__device__ __forceinline__ void gload_lds16(const void* g, void* l) {
    __builtin_amdgcn_global_load_lds(
        (const __attribute__((address_space(1))) void*)g,
        (__attribute__((address_space(3))) void*)l, 16, 0, 0);
}

// S2 layout (wave-contiguous reads): float2 index (((b*6 + mt)*4 + r)*4 + lg)*64 + fbp
__device__ __forceinline__ size_t s2i(int b, int mt, int r, int lg, int fbp) {
    return ((((size_t)b * 6 + mt) * 4 + r) * 4 + lg) * 64 + fbp;
}

__device__ __forceinline__ unsigned bfbits(float x) {
    union { __hip_bfloat16 h; unsigned short u; } cv;
    cv.h = __float2bfloat16(x);
    return (unsigned)cv.u;
}

// ---------------- Kernel 1: support = inputs @ weight, written in S2 fragment layout ----------------
__global__ __launch_bounds__(256, 4) void support_kernel(
    const float* __restrict__ inputs, const float* __restrict__ weight,
    float2* __restrict__ S2)
{
    __shared__ float in_lds[16 * F_];
    const int tid = threadIdx.x;
    const int row0 = blockIdx.x * 16;
    ((float4*)in_lds)[tid]       = ((const float4*)(inputs + (size_t)row0 * F_))[tid];
    ((float4*)in_lds)[tid + 256] = ((const float4*)(inputs + (size_t)row0 * F_))[tid + 256];
    __syncthreads();
    const int rl = tid >> 4, f0 = (tid & 15) * 8;
    float acc[8] = {0.f,0.f,0.f,0.f,0.f,0.f,0.f,0.f};
    #pragma unroll 4
    for (int k = 0; k < F_; ++k) {
        const float a = in_lds[rl * F_ + k];
        const float4 w0 = *(const float4*)(weight + k * F_ + f0);
        const float4 w1 = *(const float4*)(weight + k * F_ + f0 + 4);
        acc[0] += a * w0.x; acc[1] += a * w0.y; acc[2] += a * w0.z; acc[3] += a * w0.w;
        acc[4] += a * w1.x; acc[5] += a * w1.y; acc[6] += a * w1.z; acc[7] += a * w1.w;
    }
    const int R = row0 + rl;
    const int b = R / N_, j = R - b * N_;
    const int mt = j >> 4, lg = (j >> 2) & 3, r = j & 3;
    #pragma unroll
    for (int q = 0; q < 4; ++q) {
        const int fbp = (f0 >> 1) + q;   // f-pair index
        S2[s2i(b, mt, r, lg, fbp)] = make_float2(acc[2 * q], acc[2 * q + 1]);
    }
}

// ---------------- Kernel 2: fused attn-GEMM, overlapped convert/compute, 1 barrier/tile ----------------
// 8 waves = (4 f-slices) x (2 mt-halves). MFMA 16x16x32 k-slot fill d = ks*32+lg*8+e,
// identical for A and B (physical-k permutation cancels). C/D (HW-verified):
// col = lane&15 (-> f-pair), row = (lane>>4)*4 + reg (-> j).
__global__ __launch_bounds__(512, 4) void fused_kernel(
    const float* __restrict__ op_emb,
    const unsigned* __restrict__ adjw,      // raw 32-bit view of adj (int32 or int64)
    const float* __restrict__ attn_w,
    const float* __restrict__ attn_b,
    const float* __restrict__ self_op,
    const float2* __restrict__ S2,
    float* __restrict__ out)
{
    __shared__ __align__(16) float F32buf[3][N_ * D_];          // 3 x 18,432 B raw fp32 tiles
    __shared__ __align__(16) unsigned short Atile[2][N_ * 64];  // 2 x 12,288 B bf16; d48 mask
    __shared__ __align__(8)  float2 Ppart[2][4][16];            // wj=1 partials, parity

    const int tid  = threadIdx.x;
    const int lane = tid & 63;
    const int wid  = tid >> 6;      // wave 0..7
    const int wf   = wid & 3;       // f-slice
    const int wj   = wid >> 2;      // mt-half: mt in [3*wj, 3*wj+3)
    const int lg   = lane >> 4;
    const int lm   = lane & 15;
    const int fb   = wf * 32 + lm * 2;
    const int fbp  = wf * 16 + lm;

    const int blk = blockIdx.x;
    const int b   = blk / NGRP;
    const int grp = blk - b * NGRP;
    const int i0  = grp * G_;

    const float kNL2E = -1.44269504088896f;

    // --- adj dtype sniff: int64 little-endian has all-zero high words (values 0..4) ---
    const unsigned probe = adjw[2 * lane + 1];
    const bool use32 = __any(probe != 0);

    // issue EXACTLY 3 direct-to-LDS 1KB copies per wave for tile i -> F32buf[pb]
    auto issue_tile = [&](int i, int pb) {
        const char* gbase = (const char*)(op_emb + (size_t)(b * N_ + i) * N_ * D_);
        char* lbase = (char*)(&F32buf[pb][0]);
        #pragma unroll
        for (int c0 = 0; c0 < 3; ++c0) {
            int c = wid + 8 * c0;
            c = (c < 18) ? c : 17;          // clamp keeps per-wave vmcnt uniform
            gload_lds16(gbase + c * 1024 + lane * 16, lbase + c * 1024);
        }
    };

    // ---- prologue: issue tiles 0,1 ----
    issue_tile(i0, 0);
    issue_tile(i0 + 1, 1);

    // ---- mask codes, packed 2-bit per tile in a register (thread tid<96 owns row j=tid) ----
    unsigned mcode = 0;
    if (tid < N_) {
        #pragma unroll
        for (int g2 = 0; g2 < G_; ++g2) {
            const size_t idx = (size_t)(b * N_ + i0 + g2) * N_ + tid;
            int a = use32 ? (int)adjw[idx] : (int)adjw[2 * idx];
            a += (tid == i0 + g2) ? 1 : 0;
            const unsigned code = (a == 0) ? 0u : ((a == 1) ? 1u : 2u);
            mcode |= code << (2 * g2);
        }
    }

    // --- B fragments (attn_w pre-scaled by -log2e; d==48 -> 1.0) + bias ---
    short8 bfrag[2][2];
    float  bbias[2];
    {
        const float2 bb = *(const float2*)(attn_b + fb);
        bbias[0] = bb.x * kNL2E;
        bbias[1] = bb.y * kNL2E;
        #pragma unroll
        for (int ks = 0; ks < 2; ++ks) {
            short8 v0, v1;
            #pragma unroll
            for (int e = 0; e < 8; ++e) {
                const int d = ks * 32 + lg * 8 + e;
                if (d < D_) {
                    const float2 w = *(const float2*)(attn_w + d * F_ + fb);
                    v0[e] = (short)bfbits(w.x * kNL2E);
                    v1[e] = (short)bfbits(w.y * kNL2E);
                } else {
                    const unsigned one = (d == D_) ? bfbits(1.0f) : 0u;  // mask-slot weight
                    v0[e] = (short)one;
                    v1[e] = (short)one;
                }
            }
            bfrag[0][ks] = v0;
            bfrag[1][ks] = v1;
        }
    }

    // --- support fragments for THIS wave's mt-half (fp32, 24 regs) ---
    float2 sfrag[3][4];
    #pragma unroll
    for (int s = 0; s < 3; ++s)
        #pragma unroll
        for (int r = 0; r < 4; ++r)
            sfrag[s][r] = S2[s2i(b, 3 * wj + s, r, lg, fbp)];

    // --- zero Atile k-pad d in [50,64) of both buffers once ---
    for (int v = tid; v < 2 * N_ * 7; v += 512) {
        const int t = v / (N_ * 7);
        const int vv = v - t * (N_ * 7);
        const int j = vv / 7, q = vv - 7 * j;
        const int byte = j * 128 + ((100 + q * 4) ^ ((j & 7) << 4));
        *(unsigned*)((char*)(&Atile[t][0]) + byte) = 0u;
    }

    __syncthreads();   // drains tiles 0,1 + adj loads + pad writes (once per block)

    // convert tile gg: F32buf[gg%3] -> bf16 swizzled Atile[gg&1]; diag <- self_op; d48 <- mask
    auto convert_tile = [&](int gg) {
        const int ic = i0 + gg;
        const float* fsrc = &F32buf[gg % 3][0];
        #pragma unroll
        for (int s = 0; s < 3; ++s) {
            const int w = tid + s * 512;
            if (w < N_ * 12) {
                const int j = w / 12, c = w - 12 * j;
                float4 p;
                if (j == ic) p = *(const float4*)(self_op + c * 4);
                else         p = *(const float4*)((const char*)fsrc + 16 * w);
                const int byte = j * 128 + ((c * 8) ^ ((j & 7) << 4));
                *(uint2*)((char*)(&Atile[gg & 1][0]) + byte) =
                    make_uint2(bfbits(p.x) | (bfbits(p.y) << 16),
                               bfbits(p.z) | (bfbits(p.w) << 16));
            }
        }
        if (tid < N_) {
            const unsigned code = (mcode >> (2 * gg)) & 3u;   // shift>=24 -> 0 (dead buffer)
            // 0 -> +20 (attn ~0, sig<=4e-4), 1 -> -20 (attn ~1, err 1e-6), 2 -> 0 (sigmoid)
            // +-20 (not +-126) so 4-way d-products cannot overflow to inf.
            const unsigned bits = (code == 0) ? 0x41A0u : ((code == 1) ? 0xC1A0u : 0u);
            const int byte = tid * 128 + (96 ^ ((tid & 7) << 4));
            *(unsigned*)((char*)(&Atile[gg & 1][0]) + byte) = bits;
        }
    };

    // ---- prologue part 2: convert tile 0, make visible ----
    convert_tile(0);
    asm volatile("s_waitcnt lgkmcnt(0)" ::: "memory");
    __builtin_amdgcn_s_barrier();

    float osum_prev0 = 0.f, osum_prev1 = 0.f;

    #pragma unroll 1
    for (int g = 0; g < G_; ++g) {
        const int i = i0 + g;

        // ---- A: residual load + deferred store of tile g-1 (BEFORE issue: its implied
        //         vmcnt only drains tile-g+1 loads, which convert needs right after) ----
        if (wj == 0 && lg == 0) {
            const int ip = (g > 0) ? (i - 1) : i0;
            const float2 srv = S2[s2i(b, ip >> 4, ip & 3, (ip >> 2) & 3, fbp)];
            if (g > 0) {
                const float2 pp = Ppart[(g - 1) & 1][wf][lm];
                float2 o;
                o.x = osum_prev0 + pp.x + srv.x;
                o.y = osum_prev1 + pp.y + srv.y;
                *(float2*)(out + (size_t)(b * N_ + ip) * F_ + fb) = o;
            }
        }

        // ---- B: issue tile g+2 (clamped at tail; uniform 3 loads/wave) ----
        {
            const int inx = (g + 2 < G_) ? (g + 2) : (G_ - 1);
            issue_tile(i0 + inx, (g + 2) % 3);
        }

        // ---- W: counted wait -> tile g+1's loads landed; g+2's stay in flight ----
        if (wj == 0) asm volatile("s_waitcnt vmcnt(4)" ::: "memory");
        else         asm volatile("s_waitcnt vmcnt(3)" ::: "memory");

        // ---- C: convert tile g+1 into Atile[(g+1)&1] (overlaps compute below) ----
        convert_tile(g + 1);

        // ---- D: compute tile g from Atile[g&1]: 3 mt-slabs, MFMA + shared-rcp sigmoid ----
        __builtin_amdgcn_s_setprio(1);
        float osum0 = 0.f, osum1 = 0.f;
        #pragma unroll
        for (int s = 0; s < 3; ++s) {
            const int mt  = 3 * wj + s;
            const int jr  = mt * 16 + lm;
            const int swz = (lm & 7) << 4;
            const char* base = (const char*)(&Atile[g & 1][0]) + jr * 128;
            const short8 a0 = *(const short8*)(base + (( 0 + lg * 16) ^ swz));
            const short8 a1 = *(const short8*)(base + ((64 + lg * 16) ^ swz));
            f32x4 c0 = (f32x4){bbias[0], bbias[0], bbias[0], bbias[0]};
            f32x4 c1 = (f32x4){bbias[1], bbias[1], bbias[1], bbias[1]};
            c0 = __builtin_amdgcn_mfma_f32_16x16x32_bf16(a0, bfrag[0][0], c0, 0, 0, 0);
            c0 = __builtin_amdgcn_mfma_f32_16x16x32_bf16(a1, bfrag[0][1], c0, 0, 0, 0);
            c1 = __builtin_amdgcn_mfma_f32_16x16x32_bf16(a0, bfrag[1][0], c1, 0, 0, 0);
            c1 = __builtin_amdgcn_mfma_f32_16x16x32_bf16(a1, bfrag[1][1], c1, 0, 0, 0);
            // 4-way shared-rcp sigmoid: sig_r = rcp(d0 d1 d2 d3) * prod_{k!=r} d_k
            {
                const float d0 = 1.f + EXP2(c0[0]);
                const float d1 = 1.f + EXP2(c0[1]);
                const float d2 = 1.f + EXP2(c0[2]);
                const float d3 = 1.f + EXP2(c0[3]);
                const float d01 = d0 * d1, d23 = d2 * d3;
                const float R  = __builtin_amdgcn_rcpf(d01 * d23);
                const float Ra = R * d23, Rb = R * d01;
                osum0 = __builtin_fmaf(Ra * d1, sfrag[s][0].x, osum0);
                osum0 = __builtin_fmaf(Ra * d0, sfrag[s][1].x, osum0);
                osum0 = __builtin_fmaf(Rb * d3, sfrag[s][2].x, osum0);
                osum0 = __builtin_fmaf(Rb * d2, sfrag[s][3].x, osum0);
            }
            {
                const float d0 = 1.f + EXP2(c1[0]);
                const float d1 = 1.f + EXP2(c1[1]);
                const float d2 = 1.f + EXP2(c1[2]);
                const float d3 = 1.f + EXP2(c1[3]);
                const float d01 = d0 * d1, d23 = d2 * d3;
                const float R  = __builtin_amdgcn_rcpf(d01 * d23);
                const float Ra = R * d23, Rb = R * d01;
                osum1 = __builtin_fmaf(Ra * d1, sfrag[s][0].y, osum1);
                osum1 = __builtin_fmaf(Ra * d0, sfrag[s][1].y, osum1);
                osum1 = __builtin_fmaf(Rb * d3, sfrag[s][2].y, osum1);
                osum1 = __builtin_fmaf(Rb * d2, sfrag[s][3].y, osum1);
            }
        }
        __builtin_amdgcn_s_setprio(0);
        // reduce over the 4 lg j-subsets within the wave
        osum0 += __shfl_xor(osum0, 16);
        osum0 += __shfl_xor(osum0, 32);
        osum1 += __shfl_xor(osum1, 16);
        osum1 += __shfl_xor(osum1, 32);
        // wj=1 publishes its half (consumed next iteration, after the barrier)
        if (wj == 1 && lg == 0)
            Ppart[g & 1][wf][lm] = make_float2(osum0, osum1);
        osum_prev0 = osum0;
        osum_prev1 = osum1;

        // ---- single barrier: convert(g+1) + Ppart visible; Atile[g&1] free for reuse ----
        asm volatile("s_waitcnt lgkmcnt(0)" ::: "memory");
        __builtin_amdgcn_s_barrier();
    }

    // ---- epilogue: store the last tile ----
    if (wj == 0 && lg == 0) {
        const int ip = i0 + G_ - 1;
        const float2 pp = Ppart[(G_ - 1) & 1][wf][lm];
        const float2 sr = S2[s2i(b, ip >> 4, ip & 3, (ip >> 2) & 3, fbp)];
        float2 o;
        o.x = osum_prev0 + pp.x + sr.x;
        o.y = osum_prev1 + pp.y + sr.y;
        *(float2*)(out + (size_t)(b * N_ + ip) * F_ + fb) = o;
    }
}

extern "C" void kernel_launch(void* const* d_in, const int* in_sizes, int n_in,
                              void* d_out, int out_size, void* d_ws, size_t ws_size,
                              hipStream_t stream) {
    const float*    inputs  = (const float*)d_in[0];
    const unsigned* adjw    = (const unsigned*)d_in[1];
    const float*    op_emb  = (const float*)d_in[2];
    const float*    weight  = (const float*)d_in[3];
    const float*    attn_w  = (const float*)d_in[4];
    const float*    attn_b  = (const float*)d_in[5];
    const float*    self_op = (const float*)d_in[6];
    float* out = (float*)d_out;
    float2* S2 = (float2*)d_ws;  // fragment-layout support, 3,145,728 bytes

    support_kernel<<<(B_ * N_) / 16, 256, 0, stream>>>(inputs, weight, S2);
    fused_kernel<<<B_ * NGRP, 512, 0, stream>>>(op_emb, adjw, attn_w, attn_b, self_op,
                                                S2, out);
}